// Round 1
// baseline (257.591 us; speedup 1.0000x reference)
//
#include <hip/hip_runtime.h>

#define N_USERS 1000000
#define N_ITEMS 100000
#define EMB 16
#define OUTD 16
#define NH 4
#define HID 32
#define BB 8192
#define SS 200
#define LL 50
#define NSUPP 50000

// ---------------------------------------------------------------------------
// Kernel 1: K_supp[h][n][o] = sum_e user_embedding[supp_users[n]][e] * wk[h][e][o]
// 4 support users per 256-thread block; 64 threads (h,o) per user.
// ---------------------------------------------------------------------------
__global__ __launch_bounds__(256) void k_supp_kernel(
    const float* __restrict__ user_emb,
    const int*   __restrict__ supp_users,
    const float* __restrict__ wk,
    float*       __restrict__ Ksupp)
{
    __shared__ float s_wk[NH * EMB * OUTD];   // 1024 floats
    __shared__ float s_u[4][EMB + 1];
    int t = threadIdx.x;
    for (int i = t; i < NH * EMB * OUTD; i += 256) s_wk[i] = wk[i];
    int n0 = blockIdx.x * 4;
    if (t < 64) {
        int ul = t >> 4, e = t & 15;
        int row = supp_users[n0 + ul];
        s_u[ul][e] = user_emb[(size_t)row * EMB + e];
    }
    __syncthreads();
    int ul = t >> 6;          // which of the 4 users
    int j  = t & 63;
    int h  = j >> 4, o = j & 15;
    int n  = n0 + ul;
    float acc = 0.f;
#pragma unroll
    for (int e = 0; e < EMB; ++e)
        acc += s_u[ul][e] * s_wk[(h * EMB + e) * OUTD + o];
    Ksupp[((size_t)h * NSUPP + n) * OUTD + o] = acc;
}

// ---------------------------------------------------------------------------
// Kernel 2: user_init[b] = (sum_l item_emb[history[b][l]]) / history_len[b]
//           qbuf[b][h][o] = sum_e user_init[b][e] * wq[h][e][o]
// 16 rows (b) per 256-thread block; 16 threads (e) per row.
// NOTE: reference sums ALL L entries then divides by history_len (no masking).
// ---------------------------------------------------------------------------
__global__ __launch_bounds__(256) void user_init_q_kernel(
    const float* __restrict__ item_emb,
    const int*   __restrict__ history,
    const int*   __restrict__ history_len,
    const float* __restrict__ wq,
    float*       __restrict__ qbuf)
{
    __shared__ float s_ui[16][EMB + 1];
    __shared__ float s_wq[NH * EMB * OUTD];
    int t = threadIdx.x;
    for (int i = t; i < NH * EMB * OUTD; i += 256) s_wq[i] = wq[i];
    int bl = t >> 4, e = t & 15;
    int b  = blockIdx.x * 16 + bl;
    float sum = 0.f;
    for (int l = 0; l < LL; ++l) {
        int it = history[(size_t)b * LL + l];
        sum += item_emb[(size_t)it * EMB + e];
    }
    s_ui[bl][e] = sum / (float)history_len[b];
    __syncthreads();
    // same thread computes o = e for each head
#pragma unroll
    for (int h = 0; h < NH; ++h) {
        float acc = 0.f;
#pragma unroll
        for (int ee = 0; ee < EMB; ++ee)
            acc += s_ui[bl][ee] * s_wq[(h * EMB + ee) * OUTD + e];
        qbuf[((size_t)b * NH + h) * OUTD + e] = acc;
    }
}

// ---------------------------------------------------------------------------
// Kernel 3: per-b attention (wave h = head h) + full epilogue.
// ---------------------------------------------------------------------------
__global__ __launch_bounds__(256) void attn_epilogue_kernel(
    const float* __restrict__ Ksupp,
    const float* __restrict__ qbuf,
    const int*   __restrict__ sample_index,
    const float* __restrict__ item_emb,
    const float* __restrict__ wv,
    const float* __restrict__ w_out,
    const float* __restrict__ l1_w, const float* __restrict__ l1_b,
    const float* __restrict__ l2_w, const float* __restrict__ l2_b,
    const float* __restrict__ l3_w, const float* __restrict__ l3_b,
    const float* __restrict__ user_bias, const float* __restrict__ item_bias,
    const int*   __restrict__ x,
    float*       __restrict__ out)
{
    int b    = blockIdx.x;
    int t    = threadIdx.x;
    int h    = t >> 6;      // wave index = head
    int lane = t & 63;

    __shared__ float s_ctx[NH * OUTD];
    __shared__ float s_gat[NH * OUTD];
    __shared__ float s_ue[OUTD];
    __shared__ float s_ie[EMB];
    __shared__ float s_x1[HID];
    __shared__ float s_x2[HID / 2];

    // q for this (b,h): wave-uniform address, 16 regs
    float q[EMB];
    const float* qp = qbuf + ((size_t)b * NH + h) * OUTD;
#pragma unroll
    for (int e = 0; e < EMB; ++e) q[e] = qp[e];

    const int*   si = sample_index + ((size_t)h * BB + b) * SS;
    const float* Kh = Ksupp + (size_t)h * NSUPP * OUTD;

    float kr[4][16];
    float sc[4];
#pragma unroll
    for (int i = 0; i < 4; ++i) {
        int s = lane + 64 * i;
        if (s < SS) {
            int idx = si[s];
            const float4* kp = reinterpret_cast<const float4*>(Kh + (size_t)idx * OUTD);
            float4 a0 = kp[0], a1 = kp[1], a2 = kp[2], a3 = kp[3];
            kr[i][0]  = a0.x; kr[i][1]  = a0.y; kr[i][2]  = a0.z; kr[i][3]  = a0.w;
            kr[i][4]  = a1.x; kr[i][5]  = a1.y; kr[i][6]  = a1.z; kr[i][7]  = a1.w;
            kr[i][8]  = a2.x; kr[i][9]  = a2.y; kr[i][10] = a2.z; kr[i][11] = a2.w;
            kr[i][12] = a3.x; kr[i][13] = a3.y; kr[i][14] = a3.z; kr[i][15] = a3.w;
            float d = 0.f;
#pragma unroll
            for (int e = 0; e < EMB; ++e) d += q[e] * kr[i][e];
            sc[i] = d;
        } else {
#pragma unroll
            for (int e = 0; e < EMB; ++e) kr[i][e] = 0.f;
            sc[i] = -3.0e38f;   // exp(sc - m) == 0 exactly, no NaN
        }
    }

    // wave-wide max (64 lanes)
    float m = fmaxf(fmaxf(sc[0], sc[1]), fmaxf(sc[2], sc[3]));
#pragma unroll
    for (int off = 32; off; off >>= 1) m = fmaxf(m, __shfl_xor(m, off));

    float p[4];
    float lsum = 0.f;
#pragma unroll
    for (int i = 0; i < 4; ++i) { p[i] = __expf(sc[i] - m) * 0.f + expf(sc[i] - m); lsum += p[i]; }
#pragma unroll
    for (int off = 32; off; off >>= 1) lsum += __shfl_xor(lsum, off);

    float c[OUTD];
#pragma unroll
    for (int e = 0; e < OUTD; ++e) c[e] = 0.f;
#pragma unroll
    for (int i = 0; i < 4; ++i)
#pragma unroll
        for (int e = 0; e < OUTD; ++e) c[e] += p[i] * kr[i][e];

#pragma unroll
    for (int off = 32; off; off >>= 1)
#pragma unroll
        for (int e = 0; e < OUTD; ++e) c[e] += __shfl_xor(c[e], off);

    float inv = 1.f / lsum;
    if (lane < OUTD) s_ctx[h * OUTD + lane] = c[lane] * inv;
    __syncthreads();

    // ---------------- epilogue (tiny per-block matmuls through LDS) ---------
    int uid = x[(size_t)b * 2 + 0];
    int iid = x[(size_t)b * 2 + 1];

    if (t < EMB) s_ie[t] = item_emb[(size_t)iid * EMB + t];
    if (t < NH * OUTD) {                       // gat[h][p] = ctx[h] @ wv[h]
        int hh = t >> 4, pp = t & 15;
        float g = 0.f;
#pragma unroll
        for (int o = 0; o < OUTD; ++o) g += s_ctx[hh * OUTD + o] * wv[(hh * OUTD + o) * OUTD + pp];
        s_gat[t] = g;
    }
    __syncthreads();

    if (t < OUTD) {                            // user_emb = gat_flat @ w_out
        float acc = 0.f;
#pragma unroll
        for (int j = 0; j < NH * OUTD; ++j) acc += s_gat[j] * w_out[j * OUTD + t];
        s_ue[t] = acc;
    }
    __syncthreads();

    if (t < HID) {                             // x1 = tanh([ue, ie, ue*ie] @ l1_w + b)
        float acc = l1_b[t];
#pragma unroll
        for (int i = 0; i < EMB; ++i) {
            float ue = s_ue[i], ie = s_ie[i];
            acc += ue * l1_w[i * HID + t]
                 + ie * l1_w[(EMB + i) * HID + t]
                 + ue * ie * l1_w[(2 * EMB + i) * HID + t];
        }
        s_x1[t] = tanhf(acc);
    }
    __syncthreads();

    if (t < HID / 2) {                         // x2 = tanh(x1 @ l2_w + b)
        float acc = l2_b[t];
#pragma unroll
        for (int j = 0; j < HID; ++j) acc += s_x1[j] * l2_w[j * (HID / 2) + t];
        s_x2[t] = tanhf(acc);
    }
    __syncthreads();

    if (t == 0) {
        float x3 = l3_b[0];
#pragma unroll
        for (int j = 0; j < HID / 2; ++j) x3 += s_x2[j] * l3_w[j];
        float ratings = 0.f;
#pragma unroll
        for (int o = 0; o < OUTD; ++o) ratings += s_ue[o] * s_ie[o];
        out[b] = 0.5f * (ratings + x3) + user_bias[uid] + item_bias[iid];
    }
}

// ---------------------------------------------------------------------------
extern "C" void kernel_launch(void* const* d_in, const int* in_sizes, int n_in,
                              void* d_out, int out_size, void* d_ws, size_t ws_size,
                              hipStream_t stream) {
    const float* user_embedding = (const float*)d_in[0];
    const float* item_embedding = (const float*)d_in[1];
    const float* wq             = (const float*)d_in[2];
    const float* wk             = (const float*)d_in[3];
    const float* wv             = (const float*)d_in[4];
    const float* w_out          = (const float*)d_in[5];
    const float* l1_w           = (const float*)d_in[6];
    const float* l1_b           = (const float*)d_in[7];
    const float* l2_w           = (const float*)d_in[8];
    const float* l2_b           = (const float*)d_in[9];
    const float* l3_w           = (const float*)d_in[10];
    const float* l3_b           = (const float*)d_in[11];
    const float* user_bias      = (const float*)d_in[12];
    const float* item_bias      = (const float*)d_in[13];
    const int*   x              = (const int*)d_in[14];
    const int*   history        = (const int*)d_in[15];
    const int*   history_len    = (const int*)d_in[16];
    const int*   supp_users     = (const int*)d_in[17];
    const int*   sample_index   = (const int*)d_in[18];
    float* out = (float*)d_out;

    // workspace layout
    float* Ksupp = (float*)d_ws;                                   // 4*50000*16 f32 = 12.8 MB
    float* qbuf  = (float*)((char*)d_ws + (size_t)NH * NSUPP * OUTD * sizeof(float)); // 2 MB

    k_supp_kernel<<<NSUPP / 4, 256, 0, stream>>>(user_embedding, supp_users, wk, Ksupp);
    user_init_q_kernel<<<BB / 16, 256, 0, stream>>>(item_embedding, history, history_len, wq, qbuf);
    attn_epilogue_kernel<<<BB, 256, 0, stream>>>(
        Ksupp, qbuf, sample_index, item_embedding, wv, w_out,
        l1_w, l1_b, l2_w, l2_b, l3_w, l3_b, user_bias, item_bias, x, out);
}

// Round 2
// 242.750 us; speedup vs baseline: 1.0611x; 1.0611x over previous
//
#include <hip/hip_runtime.h>
#include <math.h>

#define N_USERS 1000000
#define N_ITEMS 100000
#define EMB 16
#define OUTD 16
#define NH 4
#define HID 32
#define BB 8192
#define SS 200
#define LL 50
#define NSUPP 50000

// ---------------------------------------------------------------------------
// Kernel 1: K_supp[h][n][o] = sum_e user_embedding[supp_users[n]][e] * wk[h][e][o]
// 16 support users per 256-thread block (3125 blocks).
// Thread t -> (h = t>>6, sub = (t>>4)&3, o = t&15), handles users sub,sub+4,+8,+12.
// Store pattern per wave: 4 x 64B chunks at consecutive n -> 256 B coalesced.
// ---------------------------------------------------------------------------
__global__ __launch_bounds__(256) void k_supp_kernel(
    const float* __restrict__ user_emb,
    const int*   __restrict__ supp_users,
    const float* __restrict__ wk,
    float*       __restrict__ Ksupp)
{
    __shared__ float s_wk[NH * EMB * OUTD];   // 1024 floats
    __shared__ float s_u[16][EMB];
    int t = threadIdx.x;
    for (int i = t; i < NH * EMB * OUTD; i += 256) s_wk[i] = wk[i];
    int n0 = blockIdx.x * 16;
    {
        int ul = t >> 4, e = t & 15;          // 256 lanes = 16 users x 16 e
        int row = supp_users[n0 + ul];
        s_u[ul][e] = user_emb[(size_t)row * EMB + e];
    }
    __syncthreads();
    int h   = t >> 6;
    int sub = (t >> 4) & 3;
    int o   = t & 15;
#pragma unroll
    for (int r = 0; r < 4; ++r) {
        int ul = sub + 4 * r;
        float acc = 0.f;
#pragma unroll
        for (int e = 0; e < EMB; ++e)
            acc += s_u[ul][e] * s_wk[(h * EMB + e) * OUTD + o];
        Ksupp[((size_t)h * NSUPP + n0 + ul) * OUTD + o] = acc;
    }
}

// ---------------------------------------------------------------------------
// Kernel 2: user_init[b] = (sum_l item_emb[history[b][l]]) / history_len[b]
//           qbuf[b][h][o] = sum_e user_init[b][e] * wq[h][e][o]
// 4 b per 256-thread block (2048 blocks); 64 threads per b = 4 l-lanes x 16 e.
// ---------------------------------------------------------------------------
__global__ __launch_bounds__(256) void user_init_q_kernel(
    const float* __restrict__ item_emb,
    const int*   __restrict__ history,
    const int*   __restrict__ history_len,
    const float* __restrict__ wq,
    float*       __restrict__ qbuf)
{
    __shared__ float s_ui[4][EMB];
    __shared__ float s_wq[NH * EMB * OUTD];
    int t = threadIdx.x;
    for (int i = t; i < NH * EMB * OUTD; i += 256) s_wq[i] = wq[i];

    int g    = t >> 6;          // which b in block
    int lane = t & 63;
    int l4   = lane >> 4;       // 0..3
    int e    = lane & 15;
    int b    = blockIdx.x * 4 + g;

    float sum = 0.f;
    for (int l = l4; l < LL; l += 4) {
        int it = history[(size_t)b * LL + l];
        sum += item_emb[(size_t)it * EMB + e];
    }
    // reduce over l4 (stride-16 lanes)
    sum += __shfl_xor(sum, 16);
    sum += __shfl_xor(sum, 32);
    if (lane < EMB) s_ui[g][lane] = sum / (float)history_len[b];
    __syncthreads();

    // 256 threads: one (g2, h, o) each -> 256 B coalesced store per wave
    int g2 = t >> 6;
    int h  = (t >> 4) & 3;
    int o  = t & 15;
    int b2 = blockIdx.x * 4 + g2;
    float acc = 0.f;
#pragma unroll
    for (int ee = 0; ee < EMB; ++ee)
        acc += s_ui[g2][ee] * s_wq[(h * EMB + ee) * OUTD + o];
    qbuf[((size_t)b2 * NH + h) * OUTD + o] = acc;
}

// ---------------------------------------------------------------------------
// Kernel 3: attention per (h, b): one wave per b, one head per block.
// XCD pinning: blockIdx%8 -> XCD (round-robin heuristic); head = (blk&7)>>1
// so each head's 3.2 MB Ksupp slab lives in one XCD pair's L2.
// Online softmax per lane: K row used while live in regs -> single gather.
// Writes gat[b][h*16+p] = (ctx @ wv[h]) (softmax-normalized).
// ---------------------------------------------------------------------------
__global__ __launch_bounds__(256) void attn_kernel(
    const float* __restrict__ Ksupp,
    const float* __restrict__ qbuf,
    const int*   __restrict__ sample_index,
    const float* __restrict__ wv,
    float*       __restrict__ gat)
{
    int blk   = blockIdx.x;
    int h     = (blk & 7) >> 1;
    int btile = ((blk >> 3) << 1) | (blk & 1);
    int wave  = threadIdx.x >> 6;
    int lane  = threadIdx.x & 63;
    int b     = btile * 4 + wave;

    float q[EMB];
    const float* qp = qbuf + ((size_t)b * NH + h) * OUTD;
#pragma unroll
    for (int e = 0; e < EMB; ++e) q[e] = qp[e];

    const int*   si = sample_index + ((size_t)h * BB + b) * SS;
    const float* Kh = Ksupp + (size_t)h * NSUPP * OUTD;

    float m = -3.0e38f, l = 0.f;
    float c[OUTD];
#pragma unroll
    for (int e = 0; e < OUTD; ++e) c[e] = 0.f;

#pragma unroll
    for (int i = 0; i < 4; ++i) {
        int s = lane + 64 * i;
        if (s < SS) {
            int idx = si[s];
            const float4* kp = reinterpret_cast<const float4*>(Kh + (size_t)idx * OUTD);
            float4 a0 = kp[0], a1 = kp[1], a2 = kp[2], a3 = kp[3];
            float k[OUTD] = {a0.x,a0.y,a0.z,a0.w, a1.x,a1.y,a1.z,a1.w,
                             a2.x,a2.y,a2.z,a2.w, a3.x,a3.y,a3.z,a3.w};
            float d = 0.f;
#pragma unroll
            for (int e = 0; e < EMB; ++e) d += q[e] * k[e];
            float mn = fmaxf(m, d);
            float sc = __expf(m - mn);   // first iter: exp(-inf) = 0
            float w  = __expf(d - mn);
            l = l * sc + w;
#pragma unroll
            for (int e = 0; e < OUTD; ++e) c[e] = c[e] * sc + w * k[e];
            m = mn;
        }
    }

    // butterfly merge of (m, l, c) across 64 lanes
#pragma unroll
    for (int off = 32; off; off >>= 1) {
        float m2 = __shfl_xor(m, off);
        float l2 = __shfl_xor(l, off);
        float mn = fmaxf(m, m2);
        float a  = __expf(m - mn);
        float bb = __expf(m2 - mn);
        l = l * a + l2 * bb;
#pragma unroll
        for (int e = 0; e < OUTD; ++e) {
            float c2 = __shfl_xor(c[e], off);
            c[e] = c[e] * a + c2 * bb;
        }
        m = mn;
    }

    float inv = 1.f / l;
    if (lane < OUTD) {
        float g = 0.f;
#pragma unroll
        for (int o = 0; o < OUTD; ++o)
            g += c[o] * wv[(h * OUTD + o) * OUTD + lane];
        gat[(size_t)b * (NH * OUTD) + h * OUTD + lane] = g * inv;
    }
}

// ---------------------------------------------------------------------------
// Kernel 4: epilogue per b (4 b per 256-thread block, one wave per b).
// ---------------------------------------------------------------------------
__global__ __launch_bounds__(256) void epilogue_kernel(
    const float* __restrict__ gat,
    const float* __restrict__ item_emb,
    const float* __restrict__ w_out,
    const float* __restrict__ l1_w, const float* __restrict__ l1_b,
    const float* __restrict__ l2_w, const float* __restrict__ l2_b,
    const float* __restrict__ l3_w, const float* __restrict__ l3_b,
    const float* __restrict__ user_bias, const float* __restrict__ item_bias,
    const int*   __restrict__ x,
    float*       __restrict__ out)
{
    int t    = threadIdx.x;
    int g    = t >> 6;
    int lane = t & 63;
    int b    = blockIdx.x * 4 + g;

    __shared__ float s_gat[4][NH * OUTD];
    __shared__ float s_ue[4][OUTD];
    __shared__ float s_ie[4][EMB];
    __shared__ float s_x1[4][HID];
    __shared__ float s_x2[4][HID / 2];

    int uid = x[(size_t)b * 2 + 0];
    int iid = x[(size_t)b * 2 + 1];

    s_gat[g][lane] = gat[(size_t)b * (NH * OUTD) + lane];
    if (lane < EMB) s_ie[g][lane] = item_emb[(size_t)iid * EMB + lane];
    __syncthreads();

    if (lane < OUTD) {
        float acc = 0.f;
#pragma unroll
        for (int j = 0; j < NH * OUTD; ++j) acc += s_gat[g][j] * w_out[j * OUTD + lane];
        s_ue[g][lane] = acc;
    }
    __syncthreads();

    if (lane < HID) {
        float acc = l1_b[lane];
#pragma unroll
        for (int i = 0; i < EMB; ++i) {
            float ue = s_ue[g][i], ie = s_ie[g][i];
            acc += ue * l1_w[i * HID + lane]
                 + ie * l1_w[(EMB + i) * HID + lane]
                 + ue * ie * l1_w[(2 * EMB + i) * HID + lane];
        }
        s_x1[g][lane] = tanhf(acc);
    }
    __syncthreads();

    if (lane < HID / 2) {
        float acc = l2_b[lane];
#pragma unroll
        for (int j = 0; j < HID; ++j) acc += s_x1[g][j] * l2_w[j * (HID / 2) + lane];
        s_x2[g][lane] = tanhf(acc);
    }
    __syncthreads();

    if (lane == 0) {
        float x3 = l3_b[0];
#pragma unroll
        for (int j = 0; j < HID / 2; ++j) x3 += s_x2[g][j] * l3_w[j];
        float ratings = 0.f;
#pragma unroll
        for (int o = 0; o < OUTD; ++o) ratings += s_ue[g][o] * s_ie[g][o];
        out[b] = 0.5f * (ratings + x3) + user_bias[uid] + item_bias[iid];
    }
}

// ---------------------------------------------------------------------------
extern "C" void kernel_launch(void* const* d_in, const int* in_sizes, int n_in,
                              void* d_out, int out_size, void* d_ws, size_t ws_size,
                              hipStream_t stream) {
    const float* user_embedding = (const float*)d_in[0];
    const float* item_embedding = (const float*)d_in[1];
    const float* wq             = (const float*)d_in[2];
    const float* wk             = (const float*)d_in[3];
    const float* wv             = (const float*)d_in[4];
    const float* w_out          = (const float*)d_in[5];
    const float* l1_w           = (const float*)d_in[6];
    const float* l1_b           = (const float*)d_in[7];
    const float* l2_w           = (const float*)d_in[8];
    const float* l2_b           = (const float*)d_in[9];
    const float* l3_w           = (const float*)d_in[10];
    const float* l3_b           = (const float*)d_in[11];
    const float* user_bias      = (const float*)d_in[12];
    const float* item_bias      = (const float*)d_in[13];
    const int*   x              = (const int*)d_in[14];
    const int*   history        = (const int*)d_in[15];
    const int*   history_len    = (const int*)d_in[16];
    const int*   supp_users     = (const int*)d_in[17];
    const int*   sample_index   = (const int*)d_in[18];
    float* out = (float*)d_out;

    // workspace layout
    char* ws = (char*)d_ws;
    float* Ksupp = (float*)ws;                                    // 4*50000*16 f32 = 12.8 MB
    ws += (size_t)NH * NSUPP * OUTD * sizeof(float);
    float* qbuf  = (float*)ws;                                    // 8192*4*16 f32 = 2 MB
    ws += (size_t)BB * NH * OUTD * sizeof(float);
    float* gat   = (float*)ws;                                    // 8192*64 f32 = 2 MB

    k_supp_kernel<<<NSUPP / 16, 256, 0, stream>>>(user_embedding, supp_users, wk, Ksupp);
    user_init_q_kernel<<<BB / 4, 256, 0, stream>>>(item_embedding, history, history_len, wq, qbuf);
    attn_kernel<<<NH * BB / 4, 256, 0, stream>>>(Ksupp, qbuf, sample_index, wv, gat);
    epilogue_kernel<<<BB / 4, 256, 0, stream>>>(
        gat, item_embedding, w_out, l1_w, l1_b, l2_w, l2_b, l3_w, l3_b,
        user_bias, item_bias, x, out);
}

// Round 4
// 237.747 us; speedup vs baseline: 1.0835x; 1.0210x over previous
//
#include <hip/hip_runtime.h>
#include <math.h>

#define N_USERS 1000000
#define N_ITEMS 100000
#define EMB 16
#define OUTD 16
#define NH 4
#define HID 32
#define BB 8192
#define SS 200
#define LL 50
#define NSUPP 50000

typedef float v4f __attribute__((ext_vector_type(4)));

// ---------------------------------------------------------------------------
// Kernel 1: K_supp[h][n][o] = sum_e user_embedding[supp_users[n]][e] * wk[h][e][o]
// 16 support users per 256-thread block (3125 blocks).
// ---------------------------------------------------------------------------
__global__ __launch_bounds__(256) void k_supp_kernel(
    const float* __restrict__ user_emb,
    const int*   __restrict__ supp_users,
    const float* __restrict__ wk,
    float*       __restrict__ Ksupp)
{
    __shared__ float s_wk[NH * EMB * OUTD];   // 1024 floats
    __shared__ float s_u[16][EMB];
    int t = threadIdx.x;
    for (int i = t; i < NH * EMB * OUTD; i += 256) s_wk[i] = wk[i];
    int n0 = blockIdx.x * 16;
    {
        int ul = t >> 4, e = t & 15;          // 256 lanes = 16 users x 16 e
        int row = supp_users[n0 + ul];
        s_u[ul][e] = user_emb[(size_t)row * EMB + e];
    }
    __syncthreads();
    int h   = t >> 6;
    int sub = (t >> 4) & 3;
    int o   = t & 15;
#pragma unroll
    for (int r = 0; r < 4; ++r) {
        int ul = sub + 4 * r;
        float acc = 0.f;
#pragma unroll
        for (int e = 0; e < EMB; ++e)
            acc += s_u[ul][e] * s_wk[(h * EMB + e) * OUTD + o];
        Ksupp[((size_t)h * NSUPP + n0 + ul) * OUTD + o] = acc;
    }
}

// ---------------------------------------------------------------------------
// Kernel 2: user_init[b] = (sum_l item_emb[history[b][l]]) / history_len[b]
//           qbuf[b][h][o] = sum_e user_init[b][e] * wq[h][e][o]
// ---------------------------------------------------------------------------
__global__ __launch_bounds__(256) void user_init_q_kernel(
    const float* __restrict__ item_emb,
    const int*   __restrict__ history,
    const int*   __restrict__ history_len,
    const float* __restrict__ wq,
    float*       __restrict__ qbuf)
{
    __shared__ float s_ui[4][EMB];
    __shared__ float s_wq[NH * EMB * OUTD];
    int t = threadIdx.x;
    for (int i = t; i < NH * EMB * OUTD; i += 256) s_wq[i] = wq[i];

    int g    = t >> 6;          // which b in block
    int lane = t & 63;
    int l4   = lane >> 4;       // 0..3
    int e    = lane & 15;
    int b    = blockIdx.x * 4 + g;

    float sum = 0.f;
    for (int l = l4; l < LL; l += 4) {
        int it = __builtin_nontemporal_load(history + (size_t)b * LL + l);
        sum += item_emb[(size_t)it * EMB + e];
    }
    sum += __shfl_xor(sum, 16);
    sum += __shfl_xor(sum, 32);
    if (lane < EMB) s_ui[g][lane] = sum / (float)history_len[b];
    __syncthreads();

    int h  = (t >> 4) & 3;
    int o  = t & 15;
    float acc = 0.f;
#pragma unroll
    for (int ee = 0; ee < EMB; ++ee)
        acc += s_ui[g][ee] * s_wq[(h * EMB + ee) * OUTD + o];
    qbuf[((size_t)b * NH + h) * OUTD + o] = acc;
}

// ---------------------------------------------------------------------------
// Kernel 3: attention per (h, b): one wave per b, one head per block.
// head = (blk&7)>>1 pins each head's 3.2 MB Ksupp slab to an XCD pair's L2
// (blockIdx % 8 -> XCD round-robin heuristic).
// NT loads for sample_index/qbuf streams so they don't evict Ksupp from L2.
// Deferred per-lane max: all 4 K rows held in regs, all loads in flight
// before any dependent math (max MLP, no serial rescale chain).
// ---------------------------------------------------------------------------
__global__ __launch_bounds__(256) void attn_kernel(
    const float* __restrict__ Ksupp,
    const float* __restrict__ qbuf,
    const int*   __restrict__ sample_index,
    const float* __restrict__ wv,
    float*       __restrict__ gat)
{
    int blk   = blockIdx.x;
    int h     = (blk & 7) >> 1;
    int btile = ((blk >> 3) << 1) | (blk & 1);
    int wave  = threadIdx.x >> 6;
    int lane  = threadIdx.x & 63;
    int b     = btile * 4 + wave;

    const int* si = sample_index + ((size_t)h * BB + b) * SS;
    // all index loads issued up front (nt: don't pollute L2)
    int idx0 = __builtin_nontemporal_load(si + lane);
    int idx1 = __builtin_nontemporal_load(si + lane + 64);
    int idx2 = __builtin_nontemporal_load(si + lane + 128);
    int idx3 = (lane < 8) ? __builtin_nontemporal_load(si + lane + 192) : 0;

    const v4f* qp = (const v4f*)(qbuf + ((size_t)b * NH + h) * OUTD);
    v4f q0 = __builtin_nontemporal_load(qp + 0);
    v4f q1 = __builtin_nontemporal_load(qp + 1);
    v4f q2 = __builtin_nontemporal_load(qp + 2);
    v4f q3 = __builtin_nontemporal_load(qp + 3);

    const float* Kh = Ksupp + (size_t)h * NSUPP * OUTD;
    const v4f* kp0 = (const v4f*)(Kh + (size_t)idx0 * OUTD);
    const v4f* kp1 = (const v4f*)(Kh + (size_t)idx1 * OUTD);
    const v4f* kp2 = (const v4f*)(Kh + (size_t)idx2 * OUTD);
    const v4f* kp3 = (const v4f*)(Kh + (size_t)idx3 * OUTD);

    // all 16 gather quads in flight (normal cached loads -> L2-resident slab)
    v4f k0a = kp0[0], k0b = kp0[1], k0c = kp0[2], k0d = kp0[3];
    v4f k1a = kp1[0], k1b = kp1[1], k1c = kp1[2], k1d = kp1[3];
    v4f k2a = kp2[0], k2b = kp2[1], k2c = kp2[2], k2d = kp2[3];
    v4f k3a = kp3[0], k3b = kp3[1], k3c = kp3[2], k3d = kp3[3];

#define DOT(ka, kb, kc, kd)                                                   \
    (ka.x*q0.x + ka.y*q0.y + ka.z*q0.z + ka.w*q0.w +                          \
     kb.x*q1.x + kb.y*q1.y + kb.z*q1.z + kb.w*q1.w +                          \
     kc.x*q2.x + kc.y*q2.y + kc.z*q2.z + kc.w*q2.w +                          \
     kd.x*q3.x + kd.y*q3.y + kd.z*q3.z + kd.w*q3.w)

    float d0 = DOT(k0a, k0b, k0c, k0d);
    float d1 = DOT(k1a, k1b, k1c, k1d);
    float d2 = DOT(k2a, k2b, k2c, k2d);
    float d3 = (lane < 8) ? DOT(k3a, k3b, k3c, k3d) : -3.0e38f;
#undef DOT

    float m = fmaxf(fmaxf(d0, d1), fmaxf(d2, d3));
    float w0 = __expf(d0 - m);
    float w1 = __expf(d1 - m);
    float w2 = __expf(d2 - m);
    float w3 = __expf(d3 - m);   // 0 for masked lanes
    float l  = w0 + w1 + w2 + w3;

    v4f ca = w0*k0a + w1*k1a + w2*k2a + w3*k3a;
    v4f cb = w0*k0b + w1*k1b + w2*k2b + w3*k3b;
    v4f cc = w0*k0c + w1*k1c + w2*k2c + w3*k3c;
    v4f cd = w0*k0d + w1*k1d + w2*k2d + w3*k3d;

    // global max across 64 lanes, then rescale once, then pure-add butterfly
    float M = m;
#pragma unroll
    for (int off = 32; off; off >>= 1) M = fmaxf(M, __shfl_xor(M, off));
    float sc = __expf(m - M);
    l *= sc; ca *= sc; cb *= sc; cc *= sc; cd *= sc;

#pragma unroll
    for (int off = 32; off; off >>= 1) {
        l += __shfl_xor(l, off);
        ca.x += __shfl_xor(ca.x, off); ca.y += __shfl_xor(ca.y, off);
        ca.z += __shfl_xor(ca.z, off); ca.w += __shfl_xor(ca.w, off);
        cb.x += __shfl_xor(cb.x, off); cb.y += __shfl_xor(cb.y, off);
        cb.z += __shfl_xor(cb.z, off); cb.w += __shfl_xor(cb.w, off);
        cc.x += __shfl_xor(cc.x, off); cc.y += __shfl_xor(cc.y, off);
        cc.z += __shfl_xor(cc.z, off); cc.w += __shfl_xor(cc.w, off);
        cd.x += __shfl_xor(cd.x, off); cd.y += __shfl_xor(cd.y, off);
        cd.z += __shfl_xor(cd.z, off); cd.w += __shfl_xor(cd.w, off);
    }

    if (lane < OUTD) {
        float c[OUTD] = {ca.x,ca.y,ca.z,ca.w, cb.x,cb.y,cb.z,cb.w,
                         cc.x,cc.y,cc.z,cc.w, cd.x,cd.y,cd.z,cd.w};
        float inv = 1.f / l;
        float g = 0.f;
#pragma unroll
        for (int o = 0; o < OUTD; ++o)
            g += c[o] * wv[(h * OUTD + o) * OUTD + lane];
        gat[(size_t)b * (NH * OUTD) + h * OUTD + lane] = g * inv;
    }
}

// ---------------------------------------------------------------------------
// Kernel 4: epilogue per b (4 b per 256-thread block, one wave per b).
// ---------------------------------------------------------------------------
__global__ __launch_bounds__(256) void epilogue_kernel(
    const float* __restrict__ gat,
    const float* __restrict__ item_emb,
    const float* __restrict__ w_out,
    const float* __restrict__ l1_w, const float* __restrict__ l1_b,
    const float* __restrict__ l2_w, const float* __restrict__ l2_b,
    const float* __restrict__ l3_w, const float* __restrict__ l3_b,
    const float* __restrict__ user_bias, const float* __restrict__ item_bias,
    const int*   __restrict__ x,
    float*       __restrict__ out)
{
    int t    = threadIdx.x;
    int g    = t >> 6;
    int lane = t & 63;
    int b    = blockIdx.x * 4 + g;

    __shared__ float s_gat[4][NH * OUTD];
    __shared__ float s_ue[4][OUTD];
    __shared__ float s_ie[4][EMB];
    __shared__ float s_x1[4][HID];
    __shared__ float s_x2[4][HID / 2];

    int uid = x[(size_t)b * 2 + 0];
    int iid = x[(size_t)b * 2 + 1];

    s_gat[g][lane] = gat[(size_t)b * (NH * OUTD) + lane];
    if (lane < EMB) s_ie[g][lane] = item_emb[(size_t)iid * EMB + lane];
    __syncthreads();

    if (lane < OUTD) {
        float acc = 0.f;
#pragma unroll
        for (int j = 0; j < NH * OUTD; ++j) acc += s_gat[g][j] * w_out[j * OUTD + lane];
        s_ue[g][lane] = acc;
    }
    __syncthreads();

    if (lane < HID) {
        float acc = l1_b[lane];
#pragma unroll
        for (int i = 0; i < EMB; ++i) {
            float ue = s_ue[g][i], ie = s_ie[g][i];
            acc += ue * l1_w[i * HID + lane]
                 + ie * l1_w[(EMB + i) * HID + lane]
                 + ue * ie * l1_w[(2 * EMB + i) * HID + lane];
        }
        s_x1[g][lane] = tanhf(acc);
    }
    __syncthreads();

    if (lane < HID / 2) {
        float acc = l2_b[lane];
#pragma unroll
        for (int j = 0; j < HID; ++j) acc += s_x1[g][j] * l2_w[j * (HID / 2) + lane];
        s_x2[g][lane] = tanhf(acc);
    }
    __syncthreads();

    if (lane == 0) {
        float x3 = l3_b[0];
#pragma unroll
        for (int j = 0; j < HID / 2; ++j) x3 += s_x2[g][j] * l3_w[j];
        float ratings = 0.f;
#pragma unroll
        for (int o = 0; o < OUTD; ++o) ratings += s_ue[g][o] * s_ie[g][o];
        out[b] = 0.5f * (ratings + x3) + user_bias[uid] + item_bias[iid];
    }
}

// ---------------------------------------------------------------------------
extern "C" void kernel_launch(void* const* d_in, const int* in_sizes, int n_in,
                              void* d_out, int out_size, void* d_ws, size_t ws_size,
                              hipStream_t stream) {
    const float* user_embedding = (const float*)d_in[0];
    const float* item_embedding = (const float*)d_in[1];
    const float* wq             = (const float*)d_in[2];
    const float* wk             = (const float*)d_in[3];
    const float* wv             = (const float*)d_in[4];
    const float* w_out          = (const float*)d_in[5];
    const float* l1_w           = (const float*)d_in[6];
    const float* l1_b           = (const float*)d_in[7];
    const float* l2_w           = (const float*)d_in[8];
    const float* l2_b           = (const float*)d_in[9];
    const float* l3_w           = (const float*)d_in[10];
    const float* l3_b           = (const float*)d_in[11];
    const float* user_bias      = (const float*)d_in[12];
    const float* item_bias      = (const float*)d_in[13];
    const int*   x              = (const int*)d_in[14];
    const int*   history        = (const int*)d_in[15];
    const int*   history_len    = (const int*)d_in[16];
    const int*   supp_users     = (const int*)d_in[17];
    const int*   sample_index   = (const int*)d_in[18];
    float* out = (float*)d_out;

    char* ws = (char*)d_ws;
    float* Ksupp = (float*)ws;                                    // 12.8 MB
    ws += (size_t)NH * NSUPP * OUTD * sizeof(float);
    float* qbuf  = (float*)ws;                                    // 2 MB
    ws += (size_t)BB * NH * OUTD * sizeof(float);
    float* gat   = (float*)ws;                                    // 2 MB

    k_supp_kernel<<<NSUPP / 16, 256, 0, stream>>>(user_embedding, supp_users, wk, Ksupp);
    user_init_q_kernel<<<BB / 4, 256, 0, stream>>>(item_embedding, history, history_len, wq, qbuf);
    attn_kernel<<<NH * BB / 4, 256, 0, stream>>>(Ksupp, qbuf, sample_index, wv, gat);
    epilogue_kernel<<<BB / 4, 256, 0, stream>>>(
        gat, item_embedding, w_out, l1_w, l1_b, l2_w, l2_b, l3_w, l3_b,
        user_bias, item_bias, x, out);
}

// Round 5
// 214.020 us; speedup vs baseline: 1.2036x; 1.1109x over previous
//
#include <hip/hip_runtime.h>
#include <math.h>

#define N_USERS 1000000
#define N_ITEMS 100000
#define EMB 16
#define OUTD 16
#define NH 4
#define HID 32
#define BB 8192
#define SS 200
#define LL 50
#define NSUPP 50000

typedef float v4f __attribute__((ext_vector_type(4)));

// ---------------------------------------------------------------------------
// Kernel 1: K_supp[h][n][o] = sum_e user_embedding[supp_users[n]][e] * wk[h][e][o]
// 16 support users per 256-thread block (3125 blocks).
// ---------------------------------------------------------------------------
__global__ __launch_bounds__(256) void k_supp_kernel(
    const float* __restrict__ user_emb,
    const int*   __restrict__ supp_users,
    const float* __restrict__ wk,
    float*       __restrict__ Ksupp)
{
    __shared__ float s_wk[NH * EMB * OUTD];   // 1024 floats
    __shared__ float s_u[16][EMB];
    int t = threadIdx.x;
    for (int i = t; i < NH * EMB * OUTD; i += 256) s_wk[i] = wk[i];
    int n0 = blockIdx.x * 16;
    {
        int ul = t >> 4, e = t & 15;          // 256 lanes = 16 users x 16 e
        int row = supp_users[n0 + ul];
        s_u[ul][e] = user_emb[(size_t)row * EMB + e];
    }
    __syncthreads();
    int h   = t >> 6;
    int sub = (t >> 4) & 3;
    int o   = t & 15;
#pragma unroll
    for (int r = 0; r < 4; ++r) {
        int ul = sub + 4 * r;
        float acc = 0.f;
#pragma unroll
        for (int e = 0; e < EMB; ++e)
            acc += s_u[ul][e] * s_wk[(h * EMB + e) * OUTD + o];
        Ksupp[((size_t)h * NSUPP + n0 + ul) * OUTD + o] = acc;
    }
}

// ---------------------------------------------------------------------------
// Kernel 2: user_init[b] = (sum_l item_emb[history[b][l]]) / history_len[b]
//           qbuf[b][h][o] = sum_e user_init[b][e] * wq[h][e][o]
// ---------------------------------------------------------------------------
__global__ __launch_bounds__(256) void user_init_q_kernel(
    const float* __restrict__ item_emb,
    const int*   __restrict__ history,
    const int*   __restrict__ history_len,
    const float* __restrict__ wq,
    float*       __restrict__ qbuf)
{
    __shared__ float s_ui[4][EMB];
    __shared__ float s_wq[NH * EMB * OUTD];
    int t = threadIdx.x;
    for (int i = t; i < NH * EMB * OUTD; i += 256) s_wq[i] = wq[i];

    int g    = t >> 6;          // which b in block
    int lane = t & 63;
    int l4   = lane >> 4;       // 0..3
    int e    = lane & 15;
    int b    = blockIdx.x * 4 + g;

    float sum = 0.f;
    for (int l = l4; l < LL; l += 4) {
        int it = __builtin_nontemporal_load(history + (size_t)b * LL + l);
        sum += item_emb[(size_t)it * EMB + e];
    }
    sum += __shfl_xor(sum, 16);
    sum += __shfl_xor(sum, 32);
    if (lane < EMB) s_ui[g][lane] = sum / (float)history_len[b];
    __syncthreads();

    int h  = (t >> 4) & 3;
    int o  = t & 15;
    float acc = 0.f;
#pragma unroll
    for (int ee = 0; ee < EMB; ++ee)
        acc += s_ui[g][ee] * s_wq[(h * EMB + ee) * OUTD + o];
    qbuf[((size_t)b * NH + h) * OUTD + o] = acc;
}

// ---------------------------------------------------------------------------
// Kernel 3: attention per (h, b): one wave per b, one head per block.
// Quad-cooperative K gather: each 64-B K row is loaded by a QUAD of lanes
// (4 x dwordx4 within one cache line) -> TA quad-coalescing merges to one
// line request; 16 unique lines per vmem instr instead of 64. Same instr
// count, 4x less address-path work (the R4 bottleneck: VALU 23%, HBM 5%,
// nothing saturated => TA/tag-lookup bound at ~64 lookups/instr).
// lane j: g = j>>2 (row slot), qt = j&3 (16-B quarter of the row).
// Round r covers samples s = r*16 + g, r = 0..12 (r=12: g<8 valid).
// ---------------------------------------------------------------------------
__global__ __launch_bounds__(256, 4) void attn_kernel(
    const float* __restrict__ Ksupp,
    const float* __restrict__ qbuf,
    const int*   __restrict__ sample_index,
    const float* __restrict__ wv,
    float*       __restrict__ gat)
{
    int blk   = blockIdx.x;
    int h     = (blk & 7) >> 1;
    int btile = ((blk >> 3) << 1) | (blk & 1);
    int wave  = threadIdx.x >> 6;
    int lane  = threadIdx.x & 63;
    int b     = btile * 4 + wave;
    int g     = lane >> 2;      // row slot within a round (16 per round)
    int qt    = lane & 3;       // which 16-B quarter of the 64-B row

    // coalesced preload of all 200 indices (nt: pure stream)
    const int* si = sample_index + ((size_t)h * BB + b) * SS;
    int pre0 = __builtin_nontemporal_load(si + lane);
    int pre1 = __builtin_nontemporal_load(si + lane + 64);
    int pre2 = __builtin_nontemporal_load(si + lane + 128);
    int pre3 = (lane < 8) ? __builtin_nontemporal_load(si + lane + 192) : 0;

    // this lane only ever needs its quarter of q
    v4f qv = __builtin_nontemporal_load(
        (const v4f*)(qbuf + ((size_t)b * NH + h) * OUTD) + qt);

    const float* Kh = Ksupp + (size_t)h * NSUPP * OUTD;

    // broadcast per-round row index to the owning quad (compile-time reg pick)
    int idx[13];
#pragma unroll
    for (int r = 0; r < 13; ++r) {
        int pre = (r < 4) ? pre0 : (r < 8) ? pre1 : (r < 12) ? pre2 : pre3;
        idx[r] = __shfl(pre, (r & 3) * 16 + g, 64);
    }

    // all 13 quad-cooperative gathers in flight
    v4f kq[13];
#pragma unroll
    for (int r = 0; r < 13; ++r)
        kq[r] = *(const v4f*)(Kh + (size_t)idx[r] * OUTD + qt * 4);

    // scores: quarter-dot + intra-quad reduce -> full dot replicated in quad
    float d[13];
#pragma unroll
    for (int r = 0; r < 13; ++r) {
        float p = kq[r].x * qv.x + kq[r].y * qv.y + kq[r].z * qv.z + kq[r].w * qv.w;
        p += __shfl_xor(p, 1);
        p += __shfl_xor(p, 2);
        d[r] = p;
    }
    if (g >= 8) d[12] = -3.0e38f;   // round 12 covers s=192..207; s<200 only

    // wave max (lanes within a quad already equal -> xor 4..32 only)
    float m = d[0];
#pragma unroll
    for (int r = 1; r < 13; ++r) m = fmaxf(m, d[r]);
#pragma unroll
    for (int off = 4; off < 64; off <<= 1) m = fmaxf(m, __shfl_xor(m, off));

    // weights + context quarter accumulation (single pass, K rows still live)
    float l = 0.f;
    v4f c = {0.f, 0.f, 0.f, 0.f};
#pragma unroll
    for (int r = 0; r < 13; ++r) {
        float w = __expf(d[r] - m);   // exactly 0 for masked slots
        l += w;
        c += w * kq[r];
    }
#pragma unroll
    for (int off = 4; off < 64; off <<= 1) {   // cross-group, qt-preserving
        l   += __shfl_xor(l, off);
        c.x += __shfl_xor(c.x, off);
        c.y += __shfl_xor(c.y, off);
        c.z += __shfl_xor(c.z, off);
        c.w += __shfl_xor(c.w, off);
    }
    float inv = 1.f / l;

    // gat[b][h*16+p]: group g owns output column p = g.
    // lane partial over its quarter's rows of wv, intra-quad reduce.
    float part = c.x * wv[((size_t)h * OUTD + qt * 4 + 0) * OUTD + g]
               + c.y * wv[((size_t)h * OUTD + qt * 4 + 1) * OUTD + g]
               + c.z * wv[((size_t)h * OUTD + qt * 4 + 2) * OUTD + g]
               + c.w * wv[((size_t)h * OUTD + qt * 4 + 3) * OUTD + g];
    part += __shfl_xor(part, 1);
    part += __shfl_xor(part, 2);
    if (qt == 0)
        gat[(size_t)b * (NH * OUTD) + h * OUTD + g] = part * inv;
}

// ---------------------------------------------------------------------------
// Kernel 4: epilogue per b (4 b per 256-thread block, one wave per b).
// ---------------------------------------------------------------------------
__global__ __launch_bounds__(256) void epilogue_kernel(
    const float* __restrict__ gat,
    const float* __restrict__ item_emb,
    const float* __restrict__ w_out,
    const float* __restrict__ l1_w, const float* __restrict__ l1_b,
    const float* __restrict__ l2_w, const float* __restrict__ l2_b,
    const float* __restrict__ l3_w, const float* __restrict__ l3_b,
    const float* __restrict__ user_bias, const float* __restrict__ item_bias,
    const int*   __restrict__ x,
    float*       __restrict__ out)
{
    int t    = threadIdx.x;
    int g    = t >> 6;
    int lane = t & 63;
    int b    = blockIdx.x * 4 + g;

    __shared__ float s_gat[4][NH * OUTD];
    __shared__ float s_ue[4][OUTD];
    __shared__ float s_ie[4][EMB];
    __shared__ float s_x1[4][HID];
    __shared__ float s_x2[4][HID / 2];

    int uid = x[(size_t)b * 2 + 0];
    int iid = x[(size_t)b * 2 + 1];

    s_gat[g][lane] = gat[(size_t)b * (NH * OUTD) + lane];
    if (lane < EMB) s_ie[g][lane] = item_emb[(size_t)iid * EMB + lane];
    __syncthreads();

    if (lane < OUTD) {
        float acc = 0.f;
#pragma unroll
        for (int j = 0; j < NH * OUTD; ++j) acc += s_gat[g][j] * w_out[j * OUTD + lane];
        s_ue[g][lane] = acc;
    }
    __syncthreads();

    if (lane < HID) {
        float acc = l1_b[lane];
#pragma unroll
        for (int i = 0; i < EMB; ++i) {
            float ue = s_ue[g][i], ie = s_ie[g][i];
            acc += ue * l1_w[i * HID + lane]
                 + ie * l1_w[(EMB + i) * HID + lane]
                 + ue * ie * l1_w[(2 * EMB + i) * HID + lane];
        }
        s_x1[g][lane] = tanhf(acc);
    }
    __syncthreads();

    if (lane < HID / 2) {
        float acc = l2_b[lane];
#pragma unroll
        for (int j = 0; j < HID; ++j) acc += s_x1[g][j] * l2_w[j * (HID / 2) + lane];
        s_x2[g][lane] = tanhf(acc);
    }
    __syncthreads();

    if (lane == 0) {
        float x3 = l3_b[0];
#pragma unroll
        for (int j = 0; j < HID / 2; ++j) x3 += s_x2[g][j] * l3_w[j];
        float ratings = 0.f;
#pragma unroll
        for (int o = 0; o < OUTD; ++o) ratings += s_ue[g][o] * s_ie[g][o];
        out[b] = 0.5f * (ratings + x3) + user_bias[uid] + item_bias[iid];
    }
}

// ---------------------------------------------------------------------------
extern "C" void kernel_launch(void* const* d_in, const int* in_sizes, int n_in,
                              void* d_out, int out_size, void* d_ws, size_t ws_size,
                              hipStream_t stream) {
    const float* user_embedding = (const float*)d_in[0];
    const float* item_embedding = (const float*)d_in[1];
    const float* wq             = (const float*)d_in[2];
    const float* wk             = (const float*)d_in[3];
    const float* wv             = (const float*)d_in[4];
    const float* w_out          = (const float*)d_in[5];
    const float* l1_w           = (const float*)d_in[6];
    const float* l1_b           = (const float*)d_in[7];
    const float* l2_w           = (const float*)d_in[8];
    const float* l2_b           = (const float*)d_in[9];
    const float* l3_w           = (const float*)d_in[10];
    const float* l3_b           = (const float*)d_in[11];
    const float* user_bias      = (const float*)d_in[12];
    const float* item_bias      = (const float*)d_in[13];
    const int*   x              = (const int*)d_in[14];
    const int*   history        = (const int*)d_in[15];
    const int*   history_len    = (const int*)d_in[16];
    const int*   supp_users     = (const int*)d_in[17];
    const int*   sample_index   = (const int*)d_in[18];
    float* out = (float*)d_out;

    char* ws = (char*)d_ws;
    float* Ksupp = (float*)ws;                                    // 12.8 MB
    ws += (size_t)NH * NSUPP * OUTD * sizeof(float);
    float* qbuf  = (float*)ws;                                    // 2 MB
    ws += (size_t)BB * NH * OUTD * sizeof(float);
    float* gat   = (float*)ws;                                    // 2 MB

    k_supp_kernel<<<NSUPP / 16, 256, 0, stream>>>(user_embedding, supp_users, wk, Ksupp);
    user_init_q_kernel<<<BB / 4, 256, 0, stream>>>(item_embedding, history, history_len, wq, qbuf);
    attn_kernel<<<NH * BB / 4, 256, 0, stream>>>(Ksupp, qbuf, sample_index, wv, gat);
    epilogue_kernel<<<BB / 4, 256, 0, stream>>>(
        gat, item_embedding, w_out, l1_w, l1_b, l2_w, l2_b, l3_w, l3_b,
        user_bias, item_bias, x, out);
}